// Round 3
// baseline (751.298 us; speedup 1.0000x reference)
//
#include <hip/hip_runtime.h>

#define N_NODES 50000
#define E_EDGES 800000
#define IN_DIM  256
#define HID     128
#define HALF    64
#define OUT_DIM 2
#define NB      16        // nodes per wave-block (50000/16 = 3125 exactly)
#define SLOPE   0.01f

// ---------------------------------------------------------------- degree ----
__global__ void zero_int_kernel(int* __restrict__ p, int n) {
    int i = blockIdx.x * blockDim.x + threadIdx.x;
    if (i < n) p[i] = 0;
}

__global__ void deg_count_kernel(const int* __restrict__ col, int* __restrict__ cnt) {
    int e = blockIdx.x * blockDim.x + threadIdx.x;
    if (e < E_EDGES) atomicAdd(&cnt[col[e]], 1);
}

// Exclusive scan of cnt[0..N) -> row_start[0..N], single 1024-thread block.
__global__ __launch_bounds__(1024) void scan_kernel(
    const int* __restrict__ cnt, int* __restrict__ row_start)
{
    __shared__ int sums[1024];
    const int T  = 1024;
    const int t  = threadIdx.x;
    const int CH = (N_NODES + T - 1) / T;   // 49
    const int base = t * CH;

    int s = 0;
    for (int k = 0; k < CH; k++) {
        int i = base + k;
        if (i < N_NODES) s += cnt[i];
    }
    sums[t] = s;
    __syncthreads();
    for (int off = 1; off < T; off <<= 1) {
        int v = (t >= off) ? sums[t - off] : 0;
        __syncthreads();
        sums[t] += v;
        __syncthreads();
    }
    int run = (t == 0) ? 0 : sums[t - 1];
    for (int k = 0; k < CH; k++) {
        int i = base + k;
        if (i < N_NODES) { row_start[i] = run; run += cnt[i]; }
    }
    if (t == T - 1) row_start[N_NODES] = run;
}

__global__ void fill_kernel(const int* __restrict__ ei,
                            const int* __restrict__ row_start,
                            int* __restrict__ cursor, int* __restrict__ csr_src)
{
    int e = blockIdx.x * blockDim.x + threadIdx.x;
    if (e >= E_EDGES) return;
    int j = ei[e];              // source
    int i = ei[E_EDGES + e];    // target
    int pos = row_start[i] + atomicAdd(&cursor[i], 1);
    csr_src[pos] = j;
}

// ------------------------------------------------------------- node phase ---
// One 64-lane wave per 16 nodes; each thread owns channels (c, c+64).
// x / weights read straight from global (x: wave-uniform broadcast, consumed
// once); only the channel->k transposes (h, s) go through LDS. No barriers.
__global__ __launch_bounds__(64, 3) void node_phase_kernel(
    const float* __restrict__ x,
    const float* __restrict__ W_in,    const float* __restrict__ b_in,
    const float* __restrict__ W_nor,   const float* __restrict__ b_nor,
    const float* __restrict__ W_abnor, const float* __restrict__ b_abnor,
    const float* __restrict__ W_att,   const float* __restrict__ b_att,
    const float* __restrict__ v_att,
    const int* __restrict__ cnt,
    float* __restrict__ u)
{
    __shared__ float hs[NB][HID];   // 8 KB: h (transposed exchange)
    __shared__ float ss[NB][HID];   // 8 KB: s = x_nor + x_abnor

    const int c0    = threadIdx.x;        // 0..63
    const int c1    = c0 + 64;
    const int node0 = blockIdx.x * NB;
    const float* xrow = x + (size_t)node0 * IN_DIM;

    // ---- h = leaky_relu(x @ W_in + b_in) ----
    float a0[NB], a1[NB];
    {
        float bi0 = b_in[c0], bi1 = b_in[c1];
        #pragma unroll
        for (int n = 0; n < NB; n++) { a0[n] = bi0; a1[n] = bi1; }
    }
    for (int k = 0; k < IN_DIM; k += 4) {
        float w00 = W_in[(k + 0) * HID + c0], w10 = W_in[(k + 0) * HID + c1];
        float w01 = W_in[(k + 1) * HID + c0], w11 = W_in[(k + 1) * HID + c1];
        float w02 = W_in[(k + 2) * HID + c0], w12 = W_in[(k + 2) * HID + c1];
        float w03 = W_in[(k + 3) * HID + c0], w13 = W_in[(k + 3) * HID + c1];
        #pragma unroll
        for (int n = 0; n < NB; n++) {
            float4 xv = *(const float4*)(xrow + (size_t)n * IN_DIM + k);
            a0[n] = fmaf(xv.x, w00, a0[n]);  a1[n] = fmaf(xv.x, w10, a1[n]);
            a0[n] = fmaf(xv.y, w01, a0[n]);  a1[n] = fmaf(xv.y, w11, a1[n]);
            a0[n] = fmaf(xv.z, w02, a0[n]);  a1[n] = fmaf(xv.z, w12, a1[n]);
            a0[n] = fmaf(xv.w, w03, a0[n]);  a1[n] = fmaf(xv.w, w13, a1[n]);
        }
    }
    #pragma unroll
    for (int n = 0; n < NB; n++) {
        float v0 = a0[n], v1 = a1[n];
        hs[n][c0] = v0 > 0.f ? v0 : SLOPE * v0;
        hs[n][c1] = v1 > 0.f ? v1 : SLOPE * v1;
    }
    // single wave: LDS ordering handled by lgkmcnt, no barrier needed

    // ---- x_nor / x_abnor from halves of h ----
    float xn0[NB], xn1[NB], xa0[NB], xa1[NB];
    {
        float bn0 = b_nor[c0],  bn1 = b_nor[c1];
        float ba0 = b_abnor[c0], ba1 = b_abnor[c1];
        #pragma unroll
        for (int n = 0; n < NB; n++) { xn0[n] = bn0; xn1[n] = bn1; xa0[n] = ba0; xa1[n] = ba1; }
    }
    for (int k = 0; k < HALF; k += 4) {
        float wn00 = W_nor[(k + 0) * HID + c0], wn10 = W_nor[(k + 0) * HID + c1];
        float wn01 = W_nor[(k + 1) * HID + c0], wn11 = W_nor[(k + 1) * HID + c1];
        float wn02 = W_nor[(k + 2) * HID + c0], wn12 = W_nor[(k + 2) * HID + c1];
        float wn03 = W_nor[(k + 3) * HID + c0], wn13 = W_nor[(k + 3) * HID + c1];
        float wa00 = W_abnor[(k + 0) * HID + c0], wa10 = W_abnor[(k + 0) * HID + c1];
        float wa01 = W_abnor[(k + 1) * HID + c0], wa11 = W_abnor[(k + 1) * HID + c1];
        float wa02 = W_abnor[(k + 2) * HID + c0], wa12 = W_abnor[(k + 2) * HID + c1];
        float wa03 = W_abnor[(k + 3) * HID + c0], wa13 = W_abnor[(k + 3) * HID + c1];
        #pragma unroll
        for (int n = 0; n < NB; n++) {
            float4 hlo = *(const float4*)&hs[n][k];
            float4 hhi = *(const float4*)&hs[n][HALF + k];
            xn0[n] = fmaf(hlo.x, wn00, xn0[n]);  xn1[n] = fmaf(hlo.x, wn10, xn1[n]);
            xn0[n] = fmaf(hlo.y, wn01, xn0[n]);  xn1[n] = fmaf(hlo.y, wn11, xn1[n]);
            xn0[n] = fmaf(hlo.z, wn02, xn0[n]);  xn1[n] = fmaf(hlo.z, wn12, xn1[n]);
            xn0[n] = fmaf(hlo.w, wn03, xn0[n]);  xn1[n] = fmaf(hlo.w, wn13, xn1[n]);
            xa0[n] = fmaf(hhi.x, wa00, xa0[n]);  xa1[n] = fmaf(hhi.x, wa10, xa1[n]);
            xa0[n] = fmaf(hhi.y, wa01, xa0[n]);  xa1[n] = fmaf(hhi.y, wa11, xa1[n]);
            xa0[n] = fmaf(hhi.z, wa02, xa0[n]);  xa1[n] = fmaf(hhi.z, wa12, xa1[n]);
            xa0[n] = fmaf(hhi.w, wa03, xa0[n]);  xa1[n] = fmaf(hhi.w, wa13, xa1[n]);
        }
    }
    #pragma unroll
    for (int n = 0; n < NB; n++) {
        ss[n][c0] = xn0[n] + xa0[n];
        ss[n][c1] = xn1[n] + xa1[n];
    }

    // ---- t = s @ W_att + b_att ----
    float t0[NB], t1[NB];
    {
        float bt0 = b_att[c0], bt1 = b_att[c1];
        #pragma unroll
        for (int n = 0; n < NB; n++) { t0[n] = bt0; t1[n] = bt1; }
    }
    for (int k = 0; k < HID; k += 4) {
        float w00 = W_att[(k + 0) * HID + c0], w10 = W_att[(k + 0) * HID + c1];
        float w01 = W_att[(k + 1) * HID + c0], w11 = W_att[(k + 1) * HID + c1];
        float w02 = W_att[(k + 2) * HID + c0], w12 = W_att[(k + 2) * HID + c1];
        float w03 = W_att[(k + 3) * HID + c0], w13 = W_att[(k + 3) * HID + c1];
        #pragma unroll
        for (int n = 0; n < NB; n++) {
            float4 sv = *(const float4*)&ss[n][k];
            t0[n] = fmaf(sv.x, w00, t0[n]);  t1[n] = fmaf(sv.x, w10, t1[n]);
            t0[n] = fmaf(sv.y, w01, t0[n]);  t1[n] = fmaf(sv.y, w11, t1[n]);
            t0[n] = fmaf(sv.z, w02, t0[n]);  t1[n] = fmaf(sv.z, w12, t1[n]);
            t0[n] = fmaf(sv.w, w03, t0[n]);  t1[n] = fmaf(sv.w, w13, t1[n]);
        }
    }

    // ---- alpha = sigmoid(sum_c tanh(t)*v) via wave butterfly ----
    float g[NB];
    {
        float vv0 = v_att[c0], vv1 = v_att[c1];
        #pragma unroll
        for (int n = 0; n < NB; n++)
            g[n] = tanhf(t0[n]) * vv0 + tanhf(t1[n]) * vv1;
    }
    #pragma unroll
    for (int m = 32; m >= 1; m >>= 1) {
        #pragma unroll
        for (int n = 0; n < NB; n++) g[n] += __shfl_xor(g[n], m, 64);
    }

    #pragma unroll
    for (int n = 0; n < NB; n++) {
        float alpha = 1.f / (1.f + expf(-g[n]));
        float dinv  = rsqrtf((float)cnt[node0 + n] + 1.0f);  // +1 self loop
        size_t o = (size_t)(node0 + n) * HID;
        u[o + c0] = dinv * (alpha * xn0[n] + (1.f - alpha) * xa0[n]);
        u[o + c1] = dinv * (alpha * xn1[n] + (1.f - alpha) * xa1[n]);
    }
}

// ------------------------------------------------------------- edge phase ---
// One wave per target node: acc[i] = u[i] + sum_{j in in(i)} u[j]
__global__ __launch_bounds__(256) void gather_kernel(
    const int* __restrict__ row_start, const int* __restrict__ csr_src,
    const float* __restrict__ u, float* __restrict__ acc)
{
    int node = blockIdx.x * 4 + (threadIdx.x >> 6);
    int lane = threadIdx.x & 63;
    if (node >= N_NODES) return;

    float2 s = *(const float2*)(u + (size_t)node * HID + lane * 2);
    int b = row_start[node], e = row_start[node + 1];
    int p = b;
    for (; p + 4 <= e; p += 4) {
        int j0 = csr_src[p + 0], j1 = csr_src[p + 1];
        int j2 = csr_src[p + 2], j3 = csr_src[p + 3];
        float2 v0 = *(const float2*)(u + (size_t)j0 * HID + lane * 2);
        float2 v1 = *(const float2*)(u + (size_t)j1 * HID + lane * 2);
        float2 v2 = *(const float2*)(u + (size_t)j2 * HID + lane * 2);
        float2 v3 = *(const float2*)(u + (size_t)j3 * HID + lane * 2);
        s.x += v0.x + v1.x + v2.x + v3.x;
        s.y += v0.y + v1.y + v2.y + v3.y;
    }
    for (; p < e; p++) {
        int j = csr_src[p];
        float2 v = *(const float2*)(u + (size_t)j * HID + lane * 2);
        s.x += v.x; s.y += v.y;
    }
    *(float2*)(acc + (size_t)node * HID + lane * 2) = s;
}

// ------------------------------------------------------------ final phase ---
// One wave per 16 nodes, 2 channels/thread; acc read uniform from global.
__global__ __launch_bounds__(64, 3) void final_phase_kernel(
    const float* __restrict__ acc, const int* __restrict__ cnt,
    const float* __restrict__ W_upd, const float* __restrict__ b_upd,
    const float* __restrict__ W_cls, const float* __restrict__ b_cls,
    float* __restrict__ out)
{
    __shared__ float us[NB][HID + 4];   // +4 pad: W_cls dot reads stride-HID

    const int c0    = threadIdx.x;
    const int c1    = c0 + 64;
    const int node0 = blockIdx.x * NB;

    float dinv[NB];
    #pragma unroll
    for (int n = 0; n < NB; n++) dinv[n] = rsqrtf((float)cnt[node0 + n] + 1.0f);

    float up0[NB], up1[NB];
    {
        float bu0 = b_upd[c0], bu1 = b_upd[c1];
        #pragma unroll
        for (int n = 0; n < NB; n++) { up0[n] = bu0; up1[n] = bu1; }
    }
    const float* arow = acc + (size_t)node0 * HID;
    for (int k = 0; k < HID; k += 4) {
        float w00 = W_upd[(k + 0) * HID + c0], w10 = W_upd[(k + 0) * HID + c1];
        float w01 = W_upd[(k + 1) * HID + c0], w11 = W_upd[(k + 1) * HID + c1];
        float w02 = W_upd[(k + 2) * HID + c0], w12 = W_upd[(k + 2) * HID + c1];
        float w03 = W_upd[(k + 3) * HID + c0], w13 = W_upd[(k + 3) * HID + c1];
        #pragma unroll
        for (int n = 0; n < NB; n++) {
            float4 av = *(const float4*)(arow + (size_t)n * HID + k);
            float d = dinv[n];
            up0[n] = fmaf(av.x * d, w00, up0[n]);  up1[n] = fmaf(av.x * d, w10, up1[n]);
            up0[n] = fmaf(av.y * d, w01, up0[n]);  up1[n] = fmaf(av.y * d, w11, up1[n]);
            up0[n] = fmaf(av.z * d, w02, up0[n]);  up1[n] = fmaf(av.z * d, w12, up1[n]);
            up0[n] = fmaf(av.w * d, w03, up0[n]);  up1[n] = fmaf(av.w * d, w13, up1[n]);
        }
    }
    #pragma unroll
    for (int n = 0; n < NB; n++) {
        float v0 = up0[n], v1 = up1[n];
        us[n][c0] = v0 > 0.f ? v0 : SLOPE * v0;
        us[n][c1] = v1 > 0.f ? v1 : SLOPE * v1;
    }
    // single wave: no barrier needed

    if (c0 < NB * OUT_DIM) {
        int n = c0 >> 1, o = c0 & 1;
        float s = b_cls[o];
        for (int k = 0; k < HID; k++)
            s = fmaf(us[n][k], W_cls[k * OUT_DIM + o], s);
        out[(size_t)(node0 + n) * OUT_DIM + o] = s;
    }
}

// ------------------------------------------------------------------ launch --
extern "C" void kernel_launch(void* const* d_in, const int* in_sizes, int n_in,
                              void* d_out, int out_size, void* d_ws, size_t ws_size,
                              hipStream_t stream)
{
    const float* x       = (const float*)d_in[0];
    const int*   ei      = (const int*)  d_in[1];   // [2, E] int32
    const float* W_in    = (const float*)d_in[2];
    const float* b_in    = (const float*)d_in[3];
    const float* W_nor   = (const float*)d_in[4];
    const float* b_nor   = (const float*)d_in[5];
    const float* W_abnor = (const float*)d_in[6];
    const float* b_abnor = (const float*)d_in[7];
    const float* W_att   = (const float*)d_in[8];
    const float* b_att   = (const float*)d_in[9];
    const float* v_att   = (const float*)d_in[10];
    const float* W_upd   = (const float*)d_in[11];
    const float* b_upd   = (const float*)d_in[12];
    const float* W_cls   = (const float*)d_in[13];
    const float* b_cls   = (const float*)d_in[14];
    float* out = (float*)d_out;

    // workspace: cnt[N] | cursor[N] | row_start[N+1] | csr_src[E] | u[N*HID] | acc[N*HID]
    int*   cnt       = (int*)d_ws;
    int*   cursor    = cnt + N_NODES;
    int*   row_start = cursor + N_NODES;
    int*   csr_src   = row_start + (N_NODES + 1);
    float* u         = (float*)(csr_src + E_EDGES);
    float* acc       = u + (size_t)N_NODES * HID;

    zero_int_kernel<<<(2 * N_NODES + 255) / 256, 256, 0, stream>>>(cnt, 2 * N_NODES);
    deg_count_kernel<<<(E_EDGES + 255) / 256, 256, 0, stream>>>(ei + E_EDGES, cnt);
    scan_kernel<<<1, 1024, 0, stream>>>(cnt, row_start);
    fill_kernel<<<(E_EDGES + 255) / 256, 256, 0, stream>>>(ei, row_start, cursor, csr_src);
    node_phase_kernel<<<N_NODES / NB, 64, 0, stream>>>(
        x, W_in, b_in, W_nor, b_nor, W_abnor, b_abnor,
        W_att, b_att, v_att, cnt, u);
    gather_kernel<<<(N_NODES + 3) / 4, 256, 0, stream>>>(row_start, csr_src, u, acc);
    final_phase_kernel<<<N_NODES / NB, 64, 0, stream>>>(
        acc, cnt, W_upd, b_upd, W_cls, b_cls, out);
}

// Round 4
// 447.904 us; speedup vs baseline: 1.6774x; 1.6774x over previous
//
#include <hip/hip_runtime.h>

#define N_NODES 50000
#define E_EDGES 800000
#define IN_DIM  256
#define HID     128
#define HALF    64
#define OUT_DIM 2
#define NB      16        // nodes per wave-block (50000/16 = 3125 exactly)
#define SLOPE   0.01f

// ---------------------------------------------------------------- degree ----
__global__ void zero_int_kernel(int* __restrict__ p, int n) {
    int i = blockIdx.x * blockDim.x + threadIdx.x;
    if (i < n) p[i] = 0;
}

__global__ void deg_count_kernel(const int* __restrict__ col, int* __restrict__ cnt) {
    int e = blockIdx.x * blockDim.x + threadIdx.x;
    if (e < E_EDGES) atomicAdd(&cnt[col[e]], 1);
}

// Exclusive scan of cnt[0..N) -> row_start[0..N], single 1024-thread block.
__global__ __launch_bounds__(1024) void scan_kernel(
    const int* __restrict__ cnt, int* __restrict__ row_start)
{
    __shared__ int sums[1024];
    const int T  = 1024;
    const int t  = threadIdx.x;
    const int CH = (N_NODES + T - 1) / T;   // 49
    const int base = t * CH;

    int s = 0;
    for (int k = 0; k < CH; k++) {
        int i = base + k;
        if (i < N_NODES) s += cnt[i];
    }
    sums[t] = s;
    __syncthreads();
    for (int off = 1; off < T; off <<= 1) {
        int v = (t >= off) ? sums[t - off] : 0;
        __syncthreads();
        sums[t] += v;
        __syncthreads();
    }
    int run = (t == 0) ? 0 : sums[t - 1];
    for (int k = 0; k < CH; k++) {
        int i = base + k;
        if (i < N_NODES) { row_start[i] = run; run += cnt[i]; }
    }
    if (t == T - 1) row_start[N_NODES] = run;
}

__global__ void fill_kernel(const int* __restrict__ ei,
                            const int* __restrict__ row_start,
                            int* __restrict__ cursor, int* __restrict__ csr_src)
{
    int e = blockIdx.x * blockDim.x + threadIdx.x;
    if (e >= E_EDGES) return;
    int j = ei[e];              // source
    int i = ei[E_EDGES + e];    // target
    int pos = row_start[i] + atomicAdd(&cursor[i], 1);
    csr_src[pos] = j;
}

// ------------------------------------------------------------- node phase ---
// One 64-lane wave per 16 nodes; lane l owns channels (2l, 2l+1) so each
// broadcast ds_read_b128 of an activation quad feeds 8 FMAs. x staged in LDS
// (coalesced); the 16 KB xs region is reused for the h / s exchanges.
__global__ __launch_bounds__(64, 3) void node_phase_kernel(
    const float* __restrict__ x,
    const float* __restrict__ W_in,    const float* __restrict__ b_in,
    const float* __restrict__ W_nor,   const float* __restrict__ b_nor,
    const float* __restrict__ W_abnor, const float* __restrict__ b_abnor,
    const float* __restrict__ W_att,   const float* __restrict__ b_att,
    const float* __restrict__ v_att,
    const int* __restrict__ cnt,
    float* __restrict__ u)
{
    __shared__ __align__(16) float smem[NB * IN_DIM];   // 16 KB, overlaid phases
    // phase A: xs[n][k]  = smem[n*256 + k]        (16 KB)
    // phase B: hs[n][c]  = smem[n*128 + c]        (first 8 KB)
    //          ss[n][c]  = smem[2048 + n*128 + c] (second 8 KB)

    const int l     = threadIdx.x;        // 0..63
    const int c0    = 2 * l;
    const int node0 = blockIdx.x * NB;
    const float* xrow = x + (size_t)node0 * IN_DIM;

    // ---- stage x (coalesced float4) ----
    for (int i = l; i < NB * IN_DIM / 4; i += 64) {
        float4 v = *(const float4*)(xrow + (size_t)i * 4);
        *(float4*)&smem[i * 4] = v;
    }
    __syncthreads();

    // ---- h = leaky_relu(x @ W_in + b_in) ----
    float a0[NB], a1[NB];
    {
        float2 bi = *(const float2*)(b_in + c0);
        #pragma unroll
        for (int n = 0; n < NB; n++) { a0[n] = bi.x; a1[n] = bi.y; }
    }
    for (int k = 0; k < IN_DIM; k += 4) {
        float2 w0 = *(const float2*)(W_in + (size_t)(k + 0) * HID + c0);
        float2 w1 = *(const float2*)(W_in + (size_t)(k + 1) * HID + c0);
        float2 w2 = *(const float2*)(W_in + (size_t)(k + 2) * HID + c0);
        float2 w3 = *(const float2*)(W_in + (size_t)(k + 3) * HID + c0);
        #pragma unroll
        for (int n = 0; n < NB; n++) {
            float4 xv = *(const float4*)&smem[n * IN_DIM + k];
            a0[n] = fmaf(xv.x, w0.x, a0[n]);  a1[n] = fmaf(xv.x, w0.y, a1[n]);
            a0[n] = fmaf(xv.y, w1.x, a0[n]);  a1[n] = fmaf(xv.y, w1.y, a1[n]);
            a0[n] = fmaf(xv.z, w2.x, a0[n]);  a1[n] = fmaf(xv.z, w2.y, a1[n]);
            a0[n] = fmaf(xv.w, w3.x, a0[n]);  a1[n] = fmaf(xv.w, w3.y, a1[n]);
        }
    }
    __syncthreads();   // xs dead; smem becomes hs/ss

    #pragma unroll
    for (int n = 0; n < NB; n++) {
        float v0 = a0[n], v1 = a1[n];
        float2 hv;
        hv.x = v0 > 0.f ? v0 : SLOPE * v0;
        hv.y = v1 > 0.f ? v1 : SLOPE * v1;
        *(float2*)&smem[n * HID + c0] = hv;
    }
    __syncthreads();

    // ---- x_nor / x_abnor from halves of h ----
    float xn0[NB], xn1[NB], xa0[NB], xa1[NB];
    {
        float2 bn = *(const float2*)(b_nor + c0);
        float2 ba = *(const float2*)(b_abnor + c0);
        #pragma unroll
        for (int n = 0; n < NB; n++) { xn0[n] = bn.x; xn1[n] = bn.y; xa0[n] = ba.x; xa1[n] = ba.y; }
    }
    for (int k = 0; k < HALF; k += 4) {
        float2 wn0 = *(const float2*)(W_nor + (size_t)(k + 0) * HID + c0);
        float2 wn1 = *(const float2*)(W_nor + (size_t)(k + 1) * HID + c0);
        float2 wn2 = *(const float2*)(W_nor + (size_t)(k + 2) * HID + c0);
        float2 wn3 = *(const float2*)(W_nor + (size_t)(k + 3) * HID + c0);
        float2 wa0 = *(const float2*)(W_abnor + (size_t)(k + 0) * HID + c0);
        float2 wa1 = *(const float2*)(W_abnor + (size_t)(k + 1) * HID + c0);
        float2 wa2 = *(const float2*)(W_abnor + (size_t)(k + 2) * HID + c0);
        float2 wa3 = *(const float2*)(W_abnor + (size_t)(k + 3) * HID + c0);
        #pragma unroll
        for (int n = 0; n < NB; n++) {
            float4 hlo = *(const float4*)&smem[n * HID + k];
            float4 hhi = *(const float4*)&smem[n * HID + HALF + k];
            xn0[n] = fmaf(hlo.x, wn0.x, xn0[n]);  xn1[n] = fmaf(hlo.x, wn0.y, xn1[n]);
            xn0[n] = fmaf(hlo.y, wn1.x, xn0[n]);  xn1[n] = fmaf(hlo.y, wn1.y, xn1[n]);
            xn0[n] = fmaf(hlo.z, wn2.x, xn0[n]);  xn1[n] = fmaf(hlo.z, wn2.y, xn1[n]);
            xn0[n] = fmaf(hlo.w, wn3.x, xn0[n]);  xn1[n] = fmaf(hlo.w, wn3.y, xn1[n]);
            xa0[n] = fmaf(hhi.x, wa0.x, xa0[n]);  xa1[n] = fmaf(hhi.x, wa0.y, xa1[n]);
            xa0[n] = fmaf(hhi.y, wa1.x, xa0[n]);  xa1[n] = fmaf(hhi.y, wa1.y, xa1[n]);
            xa0[n] = fmaf(hhi.z, wa2.x, xa0[n]);  xa1[n] = fmaf(hhi.z, wa2.y, xa1[n]);
            xa0[n] = fmaf(hhi.w, wa3.x, xa0[n]);  xa1[n] = fmaf(hhi.w, wa3.y, xa1[n]);
        }
    }
    #pragma unroll
    for (int n = 0; n < NB; n++) {
        float2 sv;
        sv.x = xn0[n] + xa0[n];
        sv.y = xn1[n] + xa1[n];
        *(float2*)&smem[NB * HID + n * HID + c0] = sv;   // ss region
    }
    __syncthreads();

    // ---- t = s @ W_att + b_att ----
    float t0[NB], t1[NB];
    {
        float2 bt = *(const float2*)(b_att + c0);
        #pragma unroll
        for (int n = 0; n < NB; n++) { t0[n] = bt.x; t1[n] = bt.y; }
    }
    for (int k = 0; k < HID; k += 4) {
        float2 w0 = *(const float2*)(W_att + (size_t)(k + 0) * HID + c0);
        float2 w1 = *(const float2*)(W_att + (size_t)(k + 1) * HID + c0);
        float2 w2 = *(const float2*)(W_att + (size_t)(k + 2) * HID + c0);
        float2 w3 = *(const float2*)(W_att + (size_t)(k + 3) * HID + c0);
        #pragma unroll
        for (int n = 0; n < NB; n++) {
            float4 sv = *(const float4*)&smem[NB * HID + n * HID + k];
            t0[n] = fmaf(sv.x, w0.x, t0[n]);  t1[n] = fmaf(sv.x, w0.y, t1[n]);
            t0[n] = fmaf(sv.y, w1.x, t0[n]);  t1[n] = fmaf(sv.y, w1.y, t1[n]);
            t0[n] = fmaf(sv.z, w2.x, t0[n]);  t1[n] = fmaf(sv.z, w2.y, t1[n]);
            t0[n] = fmaf(sv.w, w3.x, t0[n]);  t1[n] = fmaf(sv.w, w3.y, t1[n]);
        }
    }

    // ---- alpha = sigmoid(sum_c tanh(t)*v) via wave butterfly ----
    float g[NB];
    {
        float2 vv = *(const float2*)(v_att + c0);
        #pragma unroll
        for (int n = 0; n < NB; n++)
            g[n] = tanhf(t0[n]) * vv.x + tanhf(t1[n]) * vv.y;
    }
    #pragma unroll
    for (int m = 32; m >= 1; m >>= 1) {
        #pragma unroll
        for (int n = 0; n < NB; n++) g[n] += __shfl_xor(g[n], m, 64);
    }

    #pragma unroll
    for (int n = 0; n < NB; n++) {
        float alpha = 1.f / (1.f + expf(-g[n]));
        float dinv  = rsqrtf((float)cnt[node0 + n] + 1.0f);  // +1 self loop
        float2 uv;
        uv.x = dinv * (alpha * xn0[n] + (1.f - alpha) * xa0[n]);
        uv.y = dinv * (alpha * xn1[n] + (1.f - alpha) * xa1[n]);
        *(float2*)(u + (size_t)(node0 + n) * HID + c0) = uv;
    }
}

// ------------------------------------------------------------- edge phase ---
// One wave per target node: acc[i] = u[i] + sum_{j in in(i)} u[j]
__global__ __launch_bounds__(256) void gather_kernel(
    const int* __restrict__ row_start, const int* __restrict__ csr_src,
    const float* __restrict__ u, float* __restrict__ acc)
{
    int node = blockIdx.x * 4 + (threadIdx.x >> 6);
    int lane = threadIdx.x & 63;
    if (node >= N_NODES) return;

    float2 s = *(const float2*)(u + (size_t)node * HID + lane * 2);
    int b = row_start[node], e = row_start[node + 1];
    int p = b;
    for (; p + 8 <= e; p += 8) {
        int j0 = csr_src[p + 0], j1 = csr_src[p + 1];
        int j2 = csr_src[p + 2], j3 = csr_src[p + 3];
        int j4 = csr_src[p + 4], j5 = csr_src[p + 5];
        int j6 = csr_src[p + 6], j7 = csr_src[p + 7];
        float2 v0 = *(const float2*)(u + (size_t)j0 * HID + lane * 2);
        float2 v1 = *(const float2*)(u + (size_t)j1 * HID + lane * 2);
        float2 v2 = *(const float2*)(u + (size_t)j2 * HID + lane * 2);
        float2 v3 = *(const float2*)(u + (size_t)j3 * HID + lane * 2);
        float2 v4 = *(const float2*)(u + (size_t)j4 * HID + lane * 2);
        float2 v5 = *(const float2*)(u + (size_t)j5 * HID + lane * 2);
        float2 v6 = *(const float2*)(u + (size_t)j6 * HID + lane * 2);
        float2 v7 = *(const float2*)(u + (size_t)j7 * HID + lane * 2);
        s.x += v0.x + v1.x + v2.x + v3.x + v4.x + v5.x + v6.x + v7.x;
        s.y += v0.y + v1.y + v2.y + v3.y + v4.y + v5.y + v6.y + v7.y;
    }
    for (; p < e; p++) {
        int j = csr_src[p];
        float2 v = *(const float2*)(u + (size_t)j * HID + lane * 2);
        s.x += v.x; s.y += v.y;
    }
    *(float2*)(acc + (size_t)node * HID + lane * 2) = s;
}

// ------------------------------------------------------------ final phase ---
// One wave per 16 nodes; acc staged in LDS (prescaled by dinv), 2 ch/thread.
__global__ __launch_bounds__(64, 3) void final_phase_kernel(
    const float* __restrict__ acc, const int* __restrict__ cnt,
    const float* __restrict__ W_upd, const float* __restrict__ b_upd,
    const float* __restrict__ W_cls, const float* __restrict__ b_cls,
    float* __restrict__ out)
{
    __shared__ __align__(16) float as_[NB][HID];       // 8 KB (dinv-prescaled aggr)
    __shared__ float us[NB][HID + 2];                  // ~8.1 KB (post-activation)

    const int l     = threadIdx.x;
    const int c0    = 2 * l;
    const int node0 = blockIdx.x * NB;

    // stage acc, prescaled by dinv (coalesced float4; 32 float4 per row)
    const float* arow = acc + (size_t)node0 * HID;
    for (int i = l; i < NB * HID / 4; i += 64) {
        int n = i >> 5;                                // 32 float4s per row
        float d = rsqrtf((float)cnt[node0 + n] + 1.0f);
        float4 v = *(const float4*)(arow + (size_t)i * 4);
        v.x *= d; v.y *= d; v.z *= d; v.w *= d;
        *(float4*)&as_[0][i * 4] = v;
    }
    __syncthreads();

    float up0[NB], up1[NB];
    {
        float2 bu = *(const float2*)(b_upd + c0);
        #pragma unroll
        for (int n = 0; n < NB; n++) { up0[n] = bu.x; up1[n] = bu.y; }
    }
    for (int k = 0; k < HID; k += 4) {
        float2 w0 = *(const float2*)(W_upd + (size_t)(k + 0) * HID + c0);
        float2 w1 = *(const float2*)(W_upd + (size_t)(k + 1) * HID + c0);
        float2 w2 = *(const float2*)(W_upd + (size_t)(k + 2) * HID + c0);
        float2 w3 = *(const float2*)(W_upd + (size_t)(k + 3) * HID + c0);
        #pragma unroll
        for (int n = 0; n < NB; n++) {
            float4 av = *(const float4*)&as_[n][k];
            up0[n] = fmaf(av.x, w0.x, up0[n]);  up1[n] = fmaf(av.x, w0.y, up1[n]);
            up0[n] = fmaf(av.y, w1.x, up0[n]);  up1[n] = fmaf(av.y, w1.y, up1[n]);
            up0[n] = fmaf(av.z, w2.x, up0[n]);  up1[n] = fmaf(av.z, w2.y, up1[n]);
            up0[n] = fmaf(av.w, w3.x, up0[n]);  up1[n] = fmaf(av.w, w3.y, up1[n]);
        }
    }
    #pragma unroll
    for (int n = 0; n < NB; n++) {
        float v0 = up0[n], v1 = up1[n];
        us[n][c0]     = v0 > 0.f ? v0 : SLOPE * v0;
        us[n][c0 + 1] = v1 > 0.f ? v1 : SLOPE * v1;
    }
    __syncthreads();

    if (l < NB * OUT_DIM) {
        int n = l >> 1, o = l & 1;
        float s = b_cls[o];
        for (int k = 0; k < HID; k++)
            s = fmaf(us[n][k], W_cls[k * OUT_DIM + o], s);
        out[(size_t)(node0 + n) * OUT_DIM + o] = s;
    }
}

// ------------------------------------------------------------------ launch --
extern "C" void kernel_launch(void* const* d_in, const int* in_sizes, int n_in,
                              void* d_out, int out_size, void* d_ws, size_t ws_size,
                              hipStream_t stream)
{
    const float* x       = (const float*)d_in[0];
    const int*   ei      = (const int*)  d_in[1];   // [2, E] int32
    const float* W_in    = (const float*)d_in[2];
    const float* b_in    = (const float*)d_in[3];
    const float* W_nor   = (const float*)d_in[4];
    const float* b_nor   = (const float*)d_in[5];
    const float* W_abnor = (const float*)d_in[6];
    const float* b_abnor = (const float*)d_in[7];
    const float* W_att   = (const float*)d_in[8];
    const float* b_att   = (const float*)d_in[9];
    const float* v_att   = (const float*)d_in[10];
    const float* W_upd   = (const float*)d_in[11];
    const float* b_upd   = (const float*)d_in[12];
    const float* W_cls   = (const float*)d_in[13];
    const float* b_cls   = (const float*)d_in[14];
    float* out = (float*)d_out;

    // workspace: cnt[N] | cursor[N] | row_start[N+1] | csr_src[E] | u[N*HID] | acc[N*HID]
    int*   cnt       = (int*)d_ws;
    int*   cursor    = cnt + N_NODES;
    int*   row_start = cursor + N_NODES;
    int*   csr_src   = row_start + (N_NODES + 1);
    float* u         = (float*)(csr_src + E_EDGES);
    float* acc       = u + (size_t)N_NODES * HID;

    zero_int_kernel<<<(2 * N_NODES + 255) / 256, 256, 0, stream>>>(cnt, 2 * N_NODES);
    deg_count_kernel<<<(E_EDGES + 255) / 256, 256, 0, stream>>>(ei + E_EDGES, cnt);
    scan_kernel<<<1, 1024, 0, stream>>>(cnt, row_start);
    fill_kernel<<<(E_EDGES + 255) / 256, 256, 0, stream>>>(ei, row_start, cursor, csr_src);
    node_phase_kernel<<<N_NODES / NB, 64, 0, stream>>>(
        x, W_in, b_in, W_nor, b_nor, W_abnor, b_abnor,
        W_att, b_att, v_att, cnt, u);
    gather_kernel<<<(N_NODES + 3) / 4, 256, 0, stream>>>(row_start, csr_src, u, acc);
    final_phase_kernel<<<N_NODES / NB, 64, 0, stream>>>(
        acc, cnt, W_upd, b_upd, W_cls, b_cls, out);
}

// Round 5
// 410.825 us; speedup vs baseline: 1.8288x; 1.0903x over previous
//
#include <hip/hip_runtime.h>

#define N_NODES 50000
#define E_EDGES 800000
#define IN_DIM  256
#define HID     128
#define HALF    64
#define OUT_DIM 2
#define NB      16        // nodes per wave-block (50000/16 = 3125 exactly)
#define SLOPE   0.01f

#define XS_STRIDE 260     // 256 + 4 pad: broadcast-quad reads hit 16 disjoint banks
#define HS_STRIDE 132     // 128 + 4 pad: same property
#define SS_OFF    (NB * HS_STRIDE)
#define SMEM_FLOATS (2 * NB * HS_STRIDE)   // 4224 > NB*XS_STRIDE (4160)

// acc[c..c+7] += xv * W[k][c..c+7]
__device__ __forceinline__ void fma8(float* acc, float xv, float4 w0, float4 w1) {
    acc[0] = fmaf(xv, w0.x, acc[0]); acc[1] = fmaf(xv, w0.y, acc[1]);
    acc[2] = fmaf(xv, w0.z, acc[2]); acc[3] = fmaf(xv, w0.w, acc[3]);
    acc[4] = fmaf(xv, w1.x, acc[4]); acc[5] = fmaf(xv, w1.y, acc[5]);
    acc[6] = fmaf(xv, w1.z, acc[6]); acc[7] = fmaf(xv, w1.w, acc[7]);
}

// ---------------------------------------------------------------- degree ----
__global__ void zero_int_kernel(int* __restrict__ p, int n) {
    int i = blockIdx.x * blockDim.x + threadIdx.x;
    if (i < n) p[i] = 0;
}

__global__ void deg_count_kernel(const int* __restrict__ col, int* __restrict__ cnt) {
    int e = blockIdx.x * blockDim.x + threadIdx.x;
    if (e < E_EDGES) atomicAdd(&cnt[col[e]], 1);
}

// Exclusive scan of cnt[0..N) -> row_start[0..N], single 1024-thread block.
__global__ __launch_bounds__(1024) void scan_kernel(
    const int* __restrict__ cnt, int* __restrict__ row_start)
{
    __shared__ int sums[1024];
    const int T  = 1024;
    const int t  = threadIdx.x;
    const int CH = (N_NODES + T - 1) / T;   // 49
    const int base = t * CH;

    int s = 0;
    for (int k = 0; k < CH; k++) {
        int i = base + k;
        if (i < N_NODES) s += cnt[i];
    }
    sums[t] = s;
    __syncthreads();
    for (int off = 1; off < T; off <<= 1) {
        int v = (t >= off) ? sums[t - off] : 0;
        __syncthreads();
        sums[t] += v;
        __syncthreads();
    }
    int run = (t == 0) ? 0 : sums[t - 1];
    for (int k = 0; k < CH; k++) {
        int i = base + k;
        if (i < N_NODES) { row_start[i] = run; run += cnt[i]; }
    }
    if (t == T - 1) row_start[N_NODES] = run;
}

__global__ void fill_kernel(const int* __restrict__ ei,
                            const int* __restrict__ row_start,
                            int* __restrict__ cursor, int* __restrict__ csr_src)
{
    int e = blockIdx.x * blockDim.x + threadIdx.x;
    if (e >= E_EDGES) return;
    int j = ei[e];              // source
    int i = ei[E_EDGES + e];    // target
    int pos = row_start[i] + atomicAdd(&cursor[i], 1);
    csr_src[pos] = j;
}

// ------------------------------------------------------------- node phase ---
// One 64-lane wave per 16 nodes. lane = (gq = l>>4, m = l&15):
// owns channels c0=8m..8m+7 and nodes n = gq + 4r (r=0..3).
// Each broadcast ds_read_b128 of an activation quad feeds 32 FMAs.
__global__ __launch_bounds__(64, 3) void node_phase_kernel(
    const float* __restrict__ x,
    const float* __restrict__ W_in,    const float* __restrict__ b_in,
    const float* __restrict__ W_nor,   const float* __restrict__ b_nor,
    const float* __restrict__ W_abnor, const float* __restrict__ b_abnor,
    const float* __restrict__ W_att,   const float* __restrict__ b_att,
    const float* __restrict__ v_att,
    const int* __restrict__ cnt,
    float* __restrict__ u)
{
    __shared__ __align__(16) float smem[SMEM_FLOATS];   // 16.9 KB, overlaid
    // phase A: xs[n][k] = smem[n*260 + k]
    // phase B: hs[n][c] = smem[n*132 + c]; ss[n][c] = smem[SS_OFF + n*132 + c]

    const int l     = threadIdx.x;
    const int gq    = l >> 4;
    const int m     = l & 15;
    const int c0    = m * 8;
    const int node0 = blockIdx.x * NB;
    const float* xrow = x + (size_t)node0 * IN_DIM;

    // ---- stage x (coalesced global float4) ----
    #pragma unroll
    for (int it = 0; it < NB * IN_DIM / 4 / 64; it++) {
        int i = it * 64 + l;
        int n = i >> 6, kq = i & 63;
        float4 v = *(const float4*)(xrow + (size_t)i * 4);
        *(float4*)&smem[n * XS_STRIDE + kq * 4] = v;
    }
    __syncthreads();

    // ---- h = leaky_relu(x @ W_in + b_in) ----
    float a0[4][8];
    {
        float4 b0 = *(const float4*)(b_in + c0);
        float4 b1 = *(const float4*)(b_in + c0 + 4);
        #pragma unroll
        for (int r = 0; r < 4; r++) {
            a0[r][0] = b0.x; a0[r][1] = b0.y; a0[r][2] = b0.z; a0[r][3] = b0.w;
            a0[r][4] = b1.x; a0[r][5] = b1.y; a0[r][6] = b1.z; a0[r][7] = b1.w;
        }
    }
    for (int k = 0; k < IN_DIM; k += 4) {
        float4 xq[4];
        #pragma unroll
        for (int r = 0; r < 4; r++)
            xq[r] = *(const float4*)&smem[(gq + 4 * r) * XS_STRIDE + k];
        {
            float4 w0 = *(const float4*)(W_in + (size_t)(k + 0) * HID + c0);
            float4 w1 = *(const float4*)(W_in + (size_t)(k + 0) * HID + c0 + 4);
            #pragma unroll
            for (int r = 0; r < 4; r++) fma8(a0[r], xq[r].x, w0, w1);
        }
        {
            float4 w0 = *(const float4*)(W_in + (size_t)(k + 1) * HID + c0);
            float4 w1 = *(const float4*)(W_in + (size_t)(k + 1) * HID + c0 + 4);
            #pragma unroll
            for (int r = 0; r < 4; r++) fma8(a0[r], xq[r].y, w0, w1);
        }
        {
            float4 w0 = *(const float4*)(W_in + (size_t)(k + 2) * HID + c0);
            float4 w1 = *(const float4*)(W_in + (size_t)(k + 2) * HID + c0 + 4);
            #pragma unroll
            for (int r = 0; r < 4; r++) fma8(a0[r], xq[r].z, w0, w1);
        }
        {
            float4 w0 = *(const float4*)(W_in + (size_t)(k + 3) * HID + c0);
            float4 w1 = *(const float4*)(W_in + (size_t)(k + 3) * HID + c0 + 4);
            #pragma unroll
            for (int r = 0; r < 4; r++) fma8(a0[r], xq[r].w, w0, w1);
        }
    }
    __syncthreads();   // xs dead; smem becomes hs/ss

    #pragma unroll
    for (int r = 0; r < 4; r++) {
        int n = gq + 4 * r;
        float4 h0, h1;
        float v;
        v = a0[r][0]; h0.x = v > 0.f ? v : SLOPE * v;
        v = a0[r][1]; h0.y = v > 0.f ? v : SLOPE * v;
        v = a0[r][2]; h0.z = v > 0.f ? v : SLOPE * v;
        v = a0[r][3]; h0.w = v > 0.f ? v : SLOPE * v;
        v = a0[r][4]; h1.x = v > 0.f ? v : SLOPE * v;
        v = a0[r][5]; h1.y = v > 0.f ? v : SLOPE * v;
        v = a0[r][6]; h1.z = v > 0.f ? v : SLOPE * v;
        v = a0[r][7]; h1.w = v > 0.f ? v : SLOPE * v;
        *(float4*)&smem[n * HS_STRIDE + c0]     = h0;
        *(float4*)&smem[n * HS_STRIDE + c0 + 4] = h1;
    }
    __syncthreads();

    // ---- x_nor / x_abnor from halves of h ----
    float xn[4][8], xa[4][8];
    {
        float4 bn0 = *(const float4*)(b_nor + c0);
        float4 bn1 = *(const float4*)(b_nor + c0 + 4);
        float4 ba0 = *(const float4*)(b_abnor + c0);
        float4 ba1 = *(const float4*)(b_abnor + c0 + 4);
        #pragma unroll
        for (int r = 0; r < 4; r++) {
            xn[r][0] = bn0.x; xn[r][1] = bn0.y; xn[r][2] = bn0.z; xn[r][3] = bn0.w;
            xn[r][4] = bn1.x; xn[r][5] = bn1.y; xn[r][6] = bn1.z; xn[r][7] = bn1.w;
            xa[r][0] = ba0.x; xa[r][1] = ba0.y; xa[r][2] = ba0.z; xa[r][3] = ba0.w;
            xa[r][4] = ba1.x; xa[r][5] = ba1.y; xa[r][6] = ba1.z; xa[r][7] = ba1.w;
        }
    }
    for (int k = 0; k < HALF; k += 4) {
        float4 hlo[4], hhi[4];
        #pragma unroll
        for (int r = 0; r < 4; r++) {
            hlo[r] = *(const float4*)&smem[(gq + 4 * r) * HS_STRIDE + k];
            hhi[r] = *(const float4*)&smem[(gq + 4 * r) * HS_STRIDE + HALF + k];
        }
        {
            float4 wn0 = *(const float4*)(W_nor   + (size_t)(k + 0) * HID + c0);
            float4 wn1 = *(const float4*)(W_nor   + (size_t)(k + 0) * HID + c0 + 4);
            float4 wa0 = *(const float4*)(W_abnor + (size_t)(k + 0) * HID + c0);
            float4 wa1 = *(const float4*)(W_abnor + (size_t)(k + 0) * HID + c0 + 4);
            #pragma unroll
            for (int r = 0; r < 4; r++) { fma8(xn[r], hlo[r].x, wn0, wn1); fma8(xa[r], hhi[r].x, wa0, wa1); }
        }
        {
            float4 wn0 = *(const float4*)(W_nor   + (size_t)(k + 1) * HID + c0);
            float4 wn1 = *(const float4*)(W_nor   + (size_t)(k + 1) * HID + c0 + 4);
            float4 wa0 = *(const float4*)(W_abnor + (size_t)(k + 1) * HID + c0);
            float4 wa1 = *(const float4*)(W_abnor + (size_t)(k + 1) * HID + c0 + 4);
            #pragma unroll
            for (int r = 0; r < 4; r++) { fma8(xn[r], hlo[r].y, wn0, wn1); fma8(xa[r], hhi[r].y, wa0, wa1); }
        }
        {
            float4 wn0 = *(const float4*)(W_nor   + (size_t)(k + 2) * HID + c0);
            float4 wn1 = *(const float4*)(W_nor   + (size_t)(k + 2) * HID + c0 + 4);
            float4 wa0 = *(const float4*)(W_abnor + (size_t)(k + 2) * HID + c0);
            float4 wa1 = *(const float4*)(W_abnor + (size_t)(k + 2) * HID + c0 + 4);
            #pragma unroll
            for (int r = 0; r < 4; r++) { fma8(xn[r], hlo[r].z, wn0, wn1); fma8(xa[r], hhi[r].z, wa0, wa1); }
        }
        {
            float4 wn0 = *(const float4*)(W_nor   + (size_t)(k + 3) * HID + c0);
            float4 wn1 = *(const float4*)(W_nor   + (size_t)(k + 3) * HID + c0 + 4);
            float4 wa0 = *(const float4*)(W_abnor + (size_t)(k + 3) * HID + c0);
            float4 wa1 = *(const float4*)(W_abnor + (size_t)(k + 3) * HID + c0 + 4);
            #pragma unroll
            for (int r = 0; r < 4; r++) { fma8(xn[r], hlo[r].w, wn0, wn1); fma8(xa[r], hhi[r].w, wa0, wa1); }
        }
    }

    // ---- s = xn + xa -> ss region ----
    #pragma unroll
    for (int r = 0; r < 4; r++) {
        int n = gq + 4 * r;
        float4 s0, s1;
        s0.x = xn[r][0] + xa[r][0]; s0.y = xn[r][1] + xa[r][1];
        s0.z = xn[r][2] + xa[r][2]; s0.w = xn[r][3] + xa[r][3];
        s1.x = xn[r][4] + xa[r][4]; s1.y = xn[r][5] + xa[r][5];
        s1.z = xn[r][6] + xa[r][6]; s1.w = xn[r][7] + xa[r][7];
        *(float4*)&smem[SS_OFF + n * HS_STRIDE + c0]     = s0;
        *(float4*)&smem[SS_OFF + n * HS_STRIDE + c0 + 4] = s1;
    }
    __syncthreads();

    // ---- t = s @ W_att + b_att ----
    float t[4][8];
    {
        float4 b0 = *(const float4*)(b_att + c0);
        float4 b1 = *(const float4*)(b_att + c0 + 4);
        #pragma unroll
        for (int r = 0; r < 4; r++) {
            t[r][0] = b0.x; t[r][1] = b0.y; t[r][2] = b0.z; t[r][3] = b0.w;
            t[r][4] = b1.x; t[r][5] = b1.y; t[r][6] = b1.z; t[r][7] = b1.w;
        }
    }
    for (int k = 0; k < HID; k += 4) {
        float4 sq[4];
        #pragma unroll
        for (int r = 0; r < 4; r++)
            sq[r] = *(const float4*)&smem[SS_OFF + (gq + 4 * r) * HS_STRIDE + k];
        {
            float4 w0 = *(const float4*)(W_att + (size_t)(k + 0) * HID + c0);
            float4 w1 = *(const float4*)(W_att + (size_t)(k + 0) * HID + c0 + 4);
            #pragma unroll
            for (int r = 0; r < 4; r++) fma8(t[r], sq[r].x, w0, w1);
        }
        {
            float4 w0 = *(const float4*)(W_att + (size_t)(k + 1) * HID + c0);
            float4 w1 = *(const float4*)(W_att + (size_t)(k + 1) * HID + c0 + 4);
            #pragma unroll
            for (int r = 0; r < 4; r++) fma8(t[r], sq[r].y, w0, w1);
        }
        {
            float4 w0 = *(const float4*)(W_att + (size_t)(k + 2) * HID + c0);
            float4 w1 = *(const float4*)(W_att + (size_t)(k + 2) * HID + c0 + 4);
            #pragma unroll
            for (int r = 0; r < 4; r++) fma8(t[r], sq[r].z, w0, w1);
        }
        {
            float4 w0 = *(const float4*)(W_att + (size_t)(k + 3) * HID + c0);
            float4 w1 = *(const float4*)(W_att + (size_t)(k + 3) * HID + c0 + 4);
            #pragma unroll
            for (int r = 0; r < 4; r++) fma8(t[r], sq[r].w, w0, w1);
        }
    }

    // ---- alpha = sigmoid(sum_c tanh(t)*v): reduce over 16 ch-group lanes ----
    float gg[4];
    {
        float4 v0 = *(const float4*)(v_att + c0);
        float4 v1 = *(const float4*)(v_att + c0 + 4);
        #pragma unroll
        for (int r = 0; r < 4; r++) {
            gg[r] = tanhf(t[r][0]) * v0.x + tanhf(t[r][1]) * v0.y
                  + tanhf(t[r][2]) * v0.z + tanhf(t[r][3]) * v0.w
                  + tanhf(t[r][4]) * v1.x + tanhf(t[r][5]) * v1.y
                  + tanhf(t[r][6]) * v1.z + tanhf(t[r][7]) * v1.w;
        }
    }
    #pragma unroll
    for (int msk = 8; msk >= 1; msk >>= 1) {
        #pragma unroll
        for (int r = 0; r < 4; r++) gg[r] += __shfl_xor(gg[r], msk, 64);
    }

    #pragma unroll
    for (int r = 0; r < 4; r++) {
        int n = gq + 4 * r;
        float alpha = 1.f / (1.f + expf(-gg[r]));
        float beta  = 1.f - alpha;
        float dinv  = rsqrtf((float)cnt[node0 + n] + 1.0f);  // +1 self loop
        float4 o0, o1;
        o0.x = dinv * (alpha * xn[r][0] + beta * xa[r][0]);
        o0.y = dinv * (alpha * xn[r][1] + beta * xa[r][1]);
        o0.z = dinv * (alpha * xn[r][2] + beta * xa[r][2]);
        o0.w = dinv * (alpha * xn[r][3] + beta * xa[r][3]);
        o1.x = dinv * (alpha * xn[r][4] + beta * xa[r][4]);
        o1.y = dinv * (alpha * xn[r][5] + beta * xa[r][5]);
        o1.z = dinv * (alpha * xn[r][6] + beta * xa[r][6]);
        o1.w = dinv * (alpha * xn[r][7] + beta * xa[r][7]);
        *(float4*)(u + (size_t)(node0 + n) * HID + c0)     = o0;
        *(float4*)(u + (size_t)(node0 + n) * HID + c0 + 4) = o1;
    }
}

// ------------------------------------------------------------- edge phase ---
// One wave per target node: acc[i] = u[i] + sum_{j in in(i)} u[j]
__global__ __launch_bounds__(256) void gather_kernel(
    const int* __restrict__ row_start, const int* __restrict__ csr_src,
    const float* __restrict__ u, float* __restrict__ acc)
{
    int node = blockIdx.x * 4 + (threadIdx.x >> 6);
    int lane = threadIdx.x & 63;
    if (node >= N_NODES) return;

    float2 s = *(const float2*)(u + (size_t)node * HID + lane * 2);
    int b = row_start[node], e = row_start[node + 1];
    int p = b;
    for (; p + 8 <= e; p += 8) {
        int j0 = csr_src[p + 0], j1 = csr_src[p + 1];
        int j2 = csr_src[p + 2], j3 = csr_src[p + 3];
        int j4 = csr_src[p + 4], j5 = csr_src[p + 5];
        int j6 = csr_src[p + 6], j7 = csr_src[p + 7];
        float2 v0 = *(const float2*)(u + (size_t)j0 * HID + lane * 2);
        float2 v1 = *(const float2*)(u + (size_t)j1 * HID + lane * 2);
        float2 v2 = *(const float2*)(u + (size_t)j2 * HID + lane * 2);
        float2 v3 = *(const float2*)(u + (size_t)j3 * HID + lane * 2);
        float2 v4 = *(const float2*)(u + (size_t)j4 * HID + lane * 2);
        float2 v5 = *(const float2*)(u + (size_t)j5 * HID + lane * 2);
        float2 v6 = *(const float2*)(u + (size_t)j6 * HID + lane * 2);
        float2 v7 = *(const float2*)(u + (size_t)j7 * HID + lane * 2);
        s.x += v0.x + v1.x + v2.x + v3.x + v4.x + v5.x + v6.x + v7.x;
        s.y += v0.y + v1.y + v2.y + v3.y + v4.y + v5.y + v6.y + v7.y;
    }
    for (; p < e; p++) {
        int j = csr_src[p];
        float2 v = *(const float2*)(u + (size_t)j * HID + lane * 2);
        s.x += v.x; s.y += v.y;
    }
    *(float2*)(acc + (size_t)node * HID + lane * 2) = s;
}

// ------------------------------------------------------------ final phase ---
// Same (4 nodes x 8 ch)/lane tiling; acc staged in LDS prescaled by dinv.
__global__ __launch_bounds__(64, 3) void final_phase_kernel(
    const float* __restrict__ acc, const int* __restrict__ cnt,
    const float* __restrict__ W_upd, const float* __restrict__ b_upd,
    const float* __restrict__ W_cls, const float* __restrict__ b_cls,
    float* __restrict__ out)
{
    __shared__ __align__(16) float smem[SMEM_FLOATS];
    // as[n][k] = smem[n*132 + k]; us[n][c] = smem[SS_OFF + n*132 + c]

    const int l     = threadIdx.x;
    const int gq    = l >> 4;
    const int m     = l & 15;
    const int c0    = m * 8;
    const int node0 = blockIdx.x * NB;
    const float* arow = acc + (size_t)node0 * HID;

    #pragma unroll
    for (int it = 0; it < NB * HID / 4 / 64; it++) {
        int i = it * 64 + l;
        int n = i >> 5, kq = i & 31;
        float d = rsqrtf((float)cnt[node0 + n] + 1.0f);
        float4 v = *(const float4*)(arow + (size_t)i * 4);
        v.x *= d; v.y *= d; v.z *= d; v.w *= d;
        *(float4*)&smem[n * HS_STRIDE + kq * 4] = v;
    }
    __syncthreads();

    float up[4][8];
    {
        float4 b0 = *(const float4*)(b_upd + c0);
        float4 b1 = *(const float4*)(b_upd + c0 + 4);
        #pragma unroll
        for (int r = 0; r < 4; r++) {
            up[r][0] = b0.x; up[r][1] = b0.y; up[r][2] = b0.z; up[r][3] = b0.w;
            up[r][4] = b1.x; up[r][5] = b1.y; up[r][6] = b1.z; up[r][7] = b1.w;
        }
    }
    for (int k = 0; k < HID; k += 4) {
        float4 aq[4];
        #pragma unroll
        for (int r = 0; r < 4; r++)
            aq[r] = *(const float4*)&smem[(gq + 4 * r) * HS_STRIDE + k];
        {
            float4 w0 = *(const float4*)(W_upd + (size_t)(k + 0) * HID + c0);
            float4 w1 = *(const float4*)(W_upd + (size_t)(k + 0) * HID + c0 + 4);
            #pragma unroll
            for (int r = 0; r < 4; r++) fma8(up[r], aq[r].x, w0, w1);
        }
        {
            float4 w0 = *(const float4*)(W_upd + (size_t)(k + 1) * HID + c0);
            float4 w1 = *(const float4*)(W_upd + (size_t)(k + 1) * HID + c0 + 4);
            #pragma unroll
            for (int r = 0; r < 4; r++) fma8(up[r], aq[r].y, w0, w1);
        }
        {
            float4 w0 = *(const float4*)(W_upd + (size_t)(k + 2) * HID + c0);
            float4 w1 = *(const float4*)(W_upd + (size_t)(k + 2) * HID + c0 + 4);
            #pragma unroll
            for (int r = 0; r < 4; r++) fma8(up[r], aq[r].z, w0, w1);
        }
        {
            float4 w0 = *(const float4*)(W_upd + (size_t)(k + 3) * HID + c0);
            float4 w1 = *(const float4*)(W_upd + (size_t)(k + 3) * HID + c0 + 4);
            #pragma unroll
            for (int r = 0; r < 4; r++) fma8(up[r], aq[r].w, w0, w1);
        }
    }
    #pragma unroll
    for (int r = 0; r < 4; r++) {
        int n = gq + 4 * r;
        float4 u0, u1;
        float v;
        v = up[r][0]; u0.x = v > 0.f ? v : SLOPE * v;
        v = up[r][1]; u0.y = v > 0.f ? v : SLOPE * v;
        v = up[r][2]; u0.z = v > 0.f ? v : SLOPE * v;
        v = up[r][3]; u0.w = v > 0.f ? v : SLOPE * v;
        v = up[r][4]; u1.x = v > 0.f ? v : SLOPE * v;
        v = up[r][5]; u1.y = v > 0.f ? v : SLOPE * v;
        v = up[r][6]; u1.z = v > 0.f ? v : SLOPE * v;
        v = up[r][7]; u1.w = v > 0.f ? v : SLOPE * v;
        *(float4*)&smem[SS_OFF + n * HS_STRIDE + c0]     = u0;
        *(float4*)&smem[SS_OFF + n * HS_STRIDE + c0 + 4] = u1;
    }
    __syncthreads();

    if (l < NB * OUT_DIM) {
        int n = l >> 1, o = l & 1;
        float s = b_cls[o];
        for (int k = 0; k < HID; k++)
            s = fmaf(smem[SS_OFF + n * HS_STRIDE + k], W_cls[k * OUT_DIM + o], s);
        out[(size_t)(node0 + n) * OUT_DIM + o] = s;
    }
}

// ------------------------------------------------------------------ launch --
extern "C" void kernel_launch(void* const* d_in, const int* in_sizes, int n_in,
                              void* d_out, int out_size, void* d_ws, size_t ws_size,
                              hipStream_t stream)
{
    const float* x       = (const float*)d_in[0];
    const int*   ei      = (const int*)  d_in[1];   // [2, E] int32
    const float* W_in    = (const float*)d_in[2];
    const float* b_in    = (const float*)d_in[3];
    const float* W_nor   = (const float*)d_in[4];
    const float* b_nor   = (const float*)d_in[5];
    const float* W_abnor = (const float*)d_in[6];
    const float* b_abnor = (const float*)d_in[7];
    const float* W_att   = (const float*)d_in[8];
    const float* b_att   = (const float*)d_in[9];
    const float* v_att   = (const float*)d_in[10];
    const float* W_upd   = (const float*)d_in[11];
    const float* b_upd   = (const float*)d_in[12];
    const float* W_cls   = (const float*)d_in[13];
    const float* b_cls   = (const float*)d_in[14];
    float* out = (float*)d_out;

    // workspace: cnt[N] | cursor[N] | row_start[N+1] | csr_src[E] | u[N*HID] | acc[N*HID]
    int*   cnt       = (int*)d_ws;
    int*   cursor    = cnt + N_NODES;
    int*   row_start = cursor + N_NODES;
    int*   csr_src   = row_start + (N_NODES + 1);
    float* u         = (float*)(csr_src + E_EDGES);
    float* acc       = u + (size_t)N_NODES * HID;

    zero_int_kernel<<<(2 * N_NODES + 255) / 256, 256, 0, stream>>>(cnt, 2 * N_NODES);
    deg_count_kernel<<<(E_EDGES + 255) / 256, 256, 0, stream>>>(ei + E_EDGES, cnt);
    scan_kernel<<<1, 1024, 0, stream>>>(cnt, row_start);
    fill_kernel<<<(E_EDGES + 255) / 256, 256, 0, stream>>>(ei, row_start, cursor, csr_src);
    node_phase_kernel<<<N_NODES / NB, 64, 0, stream>>>(
        x, W_in, b_in, W_nor, b_nor, W_abnor, b_abnor,
        W_att, b_att, v_att, cnt, u);
    gather_kernel<<<(N_NODES + 3) / 4, 256, 0, stream>>>(row_start, csr_src, u, acc);
    final_phase_kernel<<<N_NODES / NB, 64, 0, stream>>>(
        acc, cnt, W_upd, b_upd, W_cls, b_cls, out);
}

// Round 6
// 388.854 us; speedup vs baseline: 1.9321x; 1.0565x over previous
//
#include <hip/hip_runtime.h>

#define N_NODES 50000
#define E_EDGES 800000
#define IN_DIM  256
#define HID     128
#define HALF    64
#define OUT_DIM 2
#define NB      16        // nodes per wave-block (50000/16 = 3125 exactly)
#define SLOPE   0.01f

#define HS_STRIDE 132              // 128 + 4 pad: broadcast quads hit 16 disjoint banks
#define BUF_FLOATS (NB * HS_STRIDE)   // 2112 floats = 8448 B -> ~18 blocks/CU

// acc[c..c+7] += xv * W[k][c..c+7]
__device__ __forceinline__ void fma8(float* acc, float xv, float4 w0, float4 w1) {
    acc[0] = fmaf(xv, w0.x, acc[0]); acc[1] = fmaf(xv, w0.y, acc[1]);
    acc[2] = fmaf(xv, w0.z, acc[2]); acc[3] = fmaf(xv, w0.w, acc[3]);
    acc[4] = fmaf(xv, w1.x, acc[4]); acc[5] = fmaf(xv, w1.y, acc[5]);
    acc[6] = fmaf(xv, w1.z, acc[6]); acc[7] = fmaf(xv, w1.w, acc[7]);
}

// ---------------------------------------------------------------- degree ----
__global__ void zero_int_kernel(int* __restrict__ p, int n) {
    int i = blockIdx.x * blockDim.x + threadIdx.x;
    if (i < n) p[i] = 0;
}

// cnt histogram + per-edge ticket (rank within its target bucket)
__global__ void deg_ticket_kernel(const int* __restrict__ col,
                                  int* __restrict__ cnt, int* __restrict__ ticket) {
    int e = blockIdx.x * blockDim.x + threadIdx.x;
    if (e < E_EDGES) ticket[e] = atomicAdd(&cnt[col[e]], 1);
}

// Exclusive scan of cnt[0..N) -> row_start[0..N], single 1024-thread block.
__global__ __launch_bounds__(1024) void scan_kernel(
    const int* __restrict__ cnt, int* __restrict__ row_start)
{
    __shared__ int sums[1024];
    const int T  = 1024;
    const int t  = threadIdx.x;
    const int CH = (N_NODES + T - 1) / T;   // 49
    const int base = t * CH;

    int s = 0;
    for (int k = 0; k < CH; k++) {
        int i = base + k;
        if (i < N_NODES) s += cnt[i];
    }
    sums[t] = s;
    __syncthreads();
    for (int off = 1; off < T; off <<= 1) {
        int v = (t >= off) ? sums[t - off] : 0;
        __syncthreads();
        sums[t] += v;
        __syncthreads();
    }
    int run = (t == 0) ? 0 : sums[t - 1];
    for (int k = 0; k < CH; k++) {
        int i = base + k;
        if (i < N_NODES) { row_start[i] = run; run += cnt[i]; }
    }
    if (t == T - 1) row_start[N_NODES] = run;
}

// atomic-free fill using tickets
__global__ void fill_kernel(const int* __restrict__ ei,
                            const int* __restrict__ row_start,
                            const int* __restrict__ ticket,
                            int* __restrict__ csr_src)
{
    int e = blockIdx.x * blockDim.x + threadIdx.x;
    if (e >= E_EDGES) return;
    int j = ei[e];              // source
    int i = ei[E_EDGES + e];    // target
    csr_src[row_start[i] + ticket[e]] = j;
}

// ------------------------------------------------------------- node phase ---
// One 64-lane wave per 16 nodes. lane = (gq = l>>4, m = l&15):
// owns channels c0=8m..8m+7 and nodes n = gq + 4r (r=0..3).
// Single 8.45 KB LDS buffer, overlaid: x-half -> x-half -> h -> s.
__global__ __launch_bounds__(64, 4) void node_phase_kernel(
    const float* __restrict__ x,
    const float* __restrict__ W_in,    const float* __restrict__ b_in,
    const float* __restrict__ W_nor,   const float* __restrict__ b_nor,
    const float* __restrict__ W_abnor, const float* __restrict__ b_abnor,
    const float* __restrict__ W_att,   const float* __restrict__ b_att,
    const float* __restrict__ v_att,
    const int* __restrict__ cnt,
    float* __restrict__ u)
{
    __shared__ __align__(16) float buf[BUF_FLOATS];

    const int l     = threadIdx.x;
    const int gq    = l >> 4;
    const int m     = l & 15;
    const int c0    = m * 8;
    const int node0 = blockIdx.x * NB;
    const float* xrow = x + (size_t)node0 * IN_DIM;

    // ---- h = leaky_relu(x @ W_in + b_in), k staged in two halves ----
    float a0[4][8];
    {
        float4 b0 = *(const float4*)(b_in + c0);
        float4 b1 = *(const float4*)(b_in + c0 + 4);
        #pragma unroll
        for (int r = 0; r < 4; r++) {
            a0[r][0] = b0.x; a0[r][1] = b0.y; a0[r][2] = b0.z; a0[r][3] = b0.w;
            a0[r][4] = b1.x; a0[r][5] = b1.y; a0[r][6] = b1.z; a0[r][7] = b1.w;
        }
    }
    for (int half = 0; half < 2; half++) {
        // stage 16 x-rows, k in [half*128, half*128+128)
        #pragma unroll
        for (int it = 0; it < NB * (IN_DIM / 2) / 4 / 64; it++) {   // 8
            int i = it * 64 + l;
            int n = i >> 5, kq = i & 31;
            float4 v = *(const float4*)(xrow + (size_t)n * IN_DIM + half * 128 + kq * 4);
            *(float4*)&buf[n * HS_STRIDE + kq * 4] = v;
        }
        __syncthreads();
        const float* Wh = W_in + (size_t)half * 128 * HID;
        for (int k = 0; k < 128; k += 4) {
            float4 xq[4];
            #pragma unroll
            for (int r = 0; r < 4; r++)
                xq[r] = *(const float4*)&buf[(gq + 4 * r) * HS_STRIDE + k];
            {
                float4 w0 = *(const float4*)(Wh + (size_t)(k + 0) * HID + c0);
                float4 w1 = *(const float4*)(Wh + (size_t)(k + 0) * HID + c0 + 4);
                #pragma unroll
                for (int r = 0; r < 4; r++) fma8(a0[r], xq[r].x, w0, w1);
            }
            {
                float4 w0 = *(const float4*)(Wh + (size_t)(k + 1) * HID + c0);
                float4 w1 = *(const float4*)(Wh + (size_t)(k + 1) * HID + c0 + 4);
                #pragma unroll
                for (int r = 0; r < 4; r++) fma8(a0[r], xq[r].y, w0, w1);
            }
            {
                float4 w0 = *(const float4*)(Wh + (size_t)(k + 2) * HID + c0);
                float4 w1 = *(const float4*)(Wh + (size_t)(k + 2) * HID + c0 + 4);
                #pragma unroll
                for (int r = 0; r < 4; r++) fma8(a0[r], xq[r].z, w0, w1);
            }
            {
                float4 w0 = *(const float4*)(Wh + (size_t)(k + 3) * HID + c0);
                float4 w1 = *(const float4*)(Wh + (size_t)(k + 3) * HID + c0 + 4);
                #pragma unroll
                for (int r = 0; r < 4; r++) fma8(a0[r], xq[r].w, w0, w1);
            }
        }
        __syncthreads();   // buf dead (this half consumed)
    }

    // ---- h -> buf (leaky relu) ----
    #pragma unroll
    for (int r = 0; r < 4; r++) {
        int n = gq + 4 * r;
        float4 h0, h1;
        float v;
        v = a0[r][0]; h0.x = v > 0.f ? v : SLOPE * v;
        v = a0[r][1]; h0.y = v > 0.f ? v : SLOPE * v;
        v = a0[r][2]; h0.z = v > 0.f ? v : SLOPE * v;
        v = a0[r][3]; h0.w = v > 0.f ? v : SLOPE * v;
        v = a0[r][4]; h1.x = v > 0.f ? v : SLOPE * v;
        v = a0[r][5]; h1.y = v > 0.f ? v : SLOPE * v;
        v = a0[r][6]; h1.z = v > 0.f ? v : SLOPE * v;
        v = a0[r][7]; h1.w = v > 0.f ? v : SLOPE * v;
        *(float4*)&buf[n * HS_STRIDE + c0]     = h0;
        *(float4*)&buf[n * HS_STRIDE + c0 + 4] = h1;
    }
    __syncthreads();

    // ---- x_nor / x_abnor from halves of h ----
    float xn[4][8], xa[4][8];
    {
        float4 bn0 = *(const float4*)(b_nor + c0);
        float4 bn1 = *(const float4*)(b_nor + c0 + 4);
        float4 ba0 = *(const float4*)(b_abnor + c0);
        float4 ba1 = *(const float4*)(b_abnor + c0 + 4);
        #pragma unroll
        for (int r = 0; r < 4; r++) {
            xn[r][0] = bn0.x; xn[r][1] = bn0.y; xn[r][2] = bn0.z; xn[r][3] = bn0.w;
            xn[r][4] = bn1.x; xn[r][5] = bn1.y; xn[r][6] = bn1.z; xn[r][7] = bn1.w;
            xa[r][0] = ba0.x; xa[r][1] = ba0.y; xa[r][2] = ba0.z; xa[r][3] = ba0.w;
            xa[r][4] = ba1.x; xa[r][5] = ba1.y; xa[r][6] = ba1.z; xa[r][7] = ba1.w;
        }
    }
    for (int k = 0; k < HALF; k += 4) {
        float4 hlo[4], hhi[4];
        #pragma unroll
        for (int r = 0; r < 4; r++) {
            hlo[r] = *(const float4*)&buf[(gq + 4 * r) * HS_STRIDE + k];
            hhi[r] = *(const float4*)&buf[(gq + 4 * r) * HS_STRIDE + HALF + k];
        }
        {
            float4 wn0 = *(const float4*)(W_nor   + (size_t)(k + 0) * HID + c0);
            float4 wn1 = *(const float4*)(W_nor   + (size_t)(k + 0) * HID + c0 + 4);
            float4 wa0 = *(const float4*)(W_abnor + (size_t)(k + 0) * HID + c0);
            float4 wa1 = *(const float4*)(W_abnor + (size_t)(k + 0) * HID + c0 + 4);
            #pragma unroll
            for (int r = 0; r < 4; r++) { fma8(xn[r], hlo[r].x, wn0, wn1); fma8(xa[r], hhi[r].x, wa0, wa1); }
        }
        {
            float4 wn0 = *(const float4*)(W_nor   + (size_t)(k + 1) * HID + c0);
            float4 wn1 = *(const float4*)(W_nor   + (size_t)(k + 1) * HID + c0 + 4);
            float4 wa0 = *(const float4*)(W_abnor + (size_t)(k + 1) * HID + c0);
            float4 wa1 = *(const float4*)(W_abnor + (size_t)(k + 1) * HID + c0 + 4);
            #pragma unroll
            for (int r = 0; r < 4; r++) { fma8(xn[r], hlo[r].y, wn0, wn1); fma8(xa[r], hhi[r].y, wa0, wa1); }
        }
        {
            float4 wn0 = *(const float4*)(W_nor   + (size_t)(k + 2) * HID + c0);
            float4 wn1 = *(const float4*)(W_nor   + (size_t)(k + 2) * HID + c0 + 4);
            float4 wa0 = *(const float4*)(W_abnor + (size_t)(k + 2) * HID + c0);
            float4 wa1 = *(const float4*)(W_abnor + (size_t)(k + 2) * HID + c0 + 4);
            #pragma unroll
            for (int r = 0; r < 4; r++) { fma8(xn[r], hlo[r].z, wn0, wn1); fma8(xa[r], hhi[r].z, wa0, wa1); }
        }
        {
            float4 wn0 = *(const float4*)(W_nor   + (size_t)(k + 3) * HID + c0);
            float4 wn1 = *(const float4*)(W_nor   + (size_t)(k + 3) * HID + c0 + 4);
            float4 wa0 = *(const float4*)(W_abnor + (size_t)(k + 3) * HID + c0);
            float4 wa1 = *(const float4*)(W_abnor + (size_t)(k + 3) * HID + c0 + 4);
            #pragma unroll
            for (int r = 0; r < 4; r++) { fma8(xn[r], hlo[r].w, wn0, wn1); fma8(xa[r], hhi[r].w, wa0, wa1); }
        }
    }
    __syncthreads();   // h consumed

    // ---- s = xn + xa -> buf ----
    #pragma unroll
    for (int r = 0; r < 4; r++) {
        int n = gq + 4 * r;
        float4 s0, s1;
        s0.x = xn[r][0] + xa[r][0]; s0.y = xn[r][1] + xa[r][1];
        s0.z = xn[r][2] + xa[r][2]; s0.w = xn[r][3] + xa[r][3];
        s1.x = xn[r][4] + xa[r][4]; s1.y = xn[r][5] + xa[r][5];
        s1.z = xn[r][6] + xa[r][6]; s1.w = xn[r][7] + xa[r][7];
        *(float4*)&buf[n * HS_STRIDE + c0]     = s0;
        *(float4*)&buf[n * HS_STRIDE + c0 + 4] = s1;
    }
    __syncthreads();

    // ---- t = s @ W_att + b_att ----
    float t[4][8];
    {
        float4 b0 = *(const float4*)(b_att + c0);
        float4 b1 = *(const float4*)(b_att + c0 + 4);
        #pragma unroll
        for (int r = 0; r < 4; r++) {
            t[r][0] = b0.x; t[r][1] = b0.y; t[r][2] = b0.z; t[r][3] = b0.w;
            t[r][4] = b1.x; t[r][5] = b1.y; t[r][6] = b1.z; t[r][7] = b1.w;
        }
    }
    for (int k = 0; k < HID; k += 4) {
        float4 sq[4];
        #pragma unroll
        for (int r = 0; r < 4; r++)
            sq[r] = *(const float4*)&buf[(gq + 4 * r) * HS_STRIDE + k];
        {
            float4 w0 = *(const float4*)(W_att + (size_t)(k + 0) * HID + c0);
            float4 w1 = *(const float4*)(W_att + (size_t)(k + 0) * HID + c0 + 4);
            #pragma unroll
            for (int r = 0; r < 4; r++) fma8(t[r], sq[r].x, w0, w1);
        }
        {
            float4 w0 = *(const float4*)(W_att + (size_t)(k + 1) * HID + c0);
            float4 w1 = *(const float4*)(W_att + (size_t)(k + 1) * HID + c0 + 4);
            #pragma unroll
            for (int r = 0; r < 4; r++) fma8(t[r], sq[r].y, w0, w1);
        }
        {
            float4 w0 = *(const float4*)(W_att + (size_t)(k + 2) * HID + c0);
            float4 w1 = *(const float4*)(W_att + (size_t)(k + 2) * HID + c0 + 4);
            #pragma unroll
            for (int r = 0; r < 4; r++) fma8(t[r], sq[r].z, w0, w1);
        }
        {
            float4 w0 = *(const float4*)(W_att + (size_t)(k + 3) * HID + c0);
            float4 w1 = *(const float4*)(W_att + (size_t)(k + 3) * HID + c0 + 4);
            #pragma unroll
            for (int r = 0; r < 4; r++) fma8(t[r], sq[r].w, w0, w1);
        }
    }

    // ---- alpha = sigmoid(sum_c tanh(t)*v): reduce over 16 ch-group lanes ----
    float gg[4];
    {
        float4 v0 = *(const float4*)(v_att + c0);
        float4 v1 = *(const float4*)(v_att + c0 + 4);
        #pragma unroll
        for (int r = 0; r < 4; r++) {
            gg[r] = tanhf(t[r][0]) * v0.x + tanhf(t[r][1]) * v0.y
                  + tanhf(t[r][2]) * v0.z + tanhf(t[r][3]) * v0.w
                  + tanhf(t[r][4]) * v1.x + tanhf(t[r][5]) * v1.y
                  + tanhf(t[r][6]) * v1.z + tanhf(t[r][7]) * v1.w;
        }
    }
    #pragma unroll
    for (int msk = 8; msk >= 1; msk >>= 1) {
        #pragma unroll
        for (int r = 0; r < 4; r++) gg[r] += __shfl_xor(gg[r], msk, 64);
    }

    #pragma unroll
    for (int r = 0; r < 4; r++) {
        int n = gq + 4 * r;
        float alpha = 1.f / (1.f + expf(-gg[r]));
        float beta  = 1.f - alpha;
        float dinv  = rsqrtf((float)cnt[node0 + n] + 1.0f);  // +1 self loop
        float4 o0, o1;
        o0.x = dinv * (alpha * xn[r][0] + beta * xa[r][0]);
        o0.y = dinv * (alpha * xn[r][1] + beta * xa[r][1]);
        o0.z = dinv * (alpha * xn[r][2] + beta * xa[r][2]);
        o0.w = dinv * (alpha * xn[r][3] + beta * xa[r][3]);
        o1.x = dinv * (alpha * xn[r][4] + beta * xa[r][4]);
        o1.y = dinv * (alpha * xn[r][5] + beta * xa[r][5]);
        o1.z = dinv * (alpha * xn[r][6] + beta * xa[r][6]);
        o1.w = dinv * (alpha * xn[r][7] + beta * xa[r][7]);
        *(float4*)(u + (size_t)(node0 + n) * HID + c0)     = o0;
        *(float4*)(u + (size_t)(node0 + n) * HID + c0 + 4) = o1;
    }
}

// ------------------------------------------------------------- edge phase ---
// One wave per target node: acc[i] = u[i] + sum_{j in in(i)} u[j]
__global__ __launch_bounds__(256) void gather_kernel(
    const int* __restrict__ row_start, const int* __restrict__ csr_src,
    const float* __restrict__ u, float* __restrict__ acc)
{
    int node = blockIdx.x * 4 + (threadIdx.x >> 6);
    int lane = threadIdx.x & 63;
    if (node >= N_NODES) return;

    float2 s = *(const float2*)(u + (size_t)node * HID + lane * 2);
    int b = row_start[node], e = row_start[node + 1];
    int p = b;
    for (; p + 8 <= e; p += 8) {
        int j0 = csr_src[p + 0], j1 = csr_src[p + 1];
        int j2 = csr_src[p + 2], j3 = csr_src[p + 3];
        int j4 = csr_src[p + 4], j5 = csr_src[p + 5];
        int j6 = csr_src[p + 6], j7 = csr_src[p + 7];
        float2 v0 = *(const float2*)(u + (size_t)j0 * HID + lane * 2);
        float2 v1 = *(const float2*)(u + (size_t)j1 * HID + lane * 2);
        float2 v2 = *(const float2*)(u + (size_t)j2 * HID + lane * 2);
        float2 v3 = *(const float2*)(u + (size_t)j3 * HID + lane * 2);
        float2 v4 = *(const float2*)(u + (size_t)j4 * HID + lane * 2);
        float2 v5 = *(const float2*)(u + (size_t)j5 * HID + lane * 2);
        float2 v6 = *(const float2*)(u + (size_t)j6 * HID + lane * 2);
        float2 v7 = *(const float2*)(u + (size_t)j7 * HID + lane * 2);
        s.x += v0.x + v1.x + v2.x + v3.x + v4.x + v5.x + v6.x + v7.x;
        s.y += v0.y + v1.y + v2.y + v3.y + v4.y + v5.y + v6.y + v7.y;
    }
    for (; p < e; p++) {
        int j = csr_src[p];
        float2 v = *(const float2*)(u + (size_t)j * HID + lane * 2);
        s.x += v.x; s.y += v.y;
    }
    *(float2*)(acc + (size_t)node * HID + lane * 2) = s;
}

// ------------------------------------------------------------ final phase ---
// Same (4 nodes x 8 ch)/lane tiling; one 8.45 KB buffer overlaid: as -> us.
__global__ __launch_bounds__(64, 4) void final_phase_kernel(
    const float* __restrict__ acc, const int* __restrict__ cnt,
    const float* __restrict__ W_upd, const float* __restrict__ b_upd,
    const float* __restrict__ W_cls, const float* __restrict__ b_cls,
    float* __restrict__ out)
{
    __shared__ __align__(16) float buf[BUF_FLOATS];

    const int l     = threadIdx.x;
    const int gq    = l >> 4;
    const int m     = l & 15;
    const int c0    = m * 8;
    const int node0 = blockIdx.x * NB;
    const float* arow = acc + (size_t)node0 * HID;

    // stage acc prescaled by dinv
    #pragma unroll
    for (int it = 0; it < NB * HID / 4 / 64; it++) {   // 8
        int i = it * 64 + l;
        int n = i >> 5, kq = i & 31;
        float d = rsqrtf((float)cnt[node0 + n] + 1.0f);
        float4 v = *(const float4*)(arow + (size_t)i * 4);
        v.x *= d; v.y *= d; v.z *= d; v.w *= d;
        *(float4*)&buf[n * HS_STRIDE + kq * 4] = v;
    }
    __syncthreads();

    float up[4][8];
    {
        float4 b0 = *(const float4*)(b_upd + c0);
        float4 b1 = *(const float4*)(b_upd + c0 + 4);
        #pragma unroll
        for (int r = 0; r < 4; r++) {
            up[r][0] = b0.x; up[r][1] = b0.y; up[r][2] = b0.z; up[r][3] = b0.w;
            up[r][4] = b1.x; up[r][5] = b1.y; up[r][6] = b1.z; up[r][7] = b1.w;
        }
    }
    for (int k = 0; k < HID; k += 4) {
        float4 aq[4];
        #pragma unroll
        for (int r = 0; r < 4; r++)
            aq[r] = *(const float4*)&buf[(gq + 4 * r) * HS_STRIDE + k];
        {
            float4 w0 = *(const float4*)(W_upd + (size_t)(k + 0) * HID + c0);
            float4 w1 = *(const float4*)(W_upd + (size_t)(k + 0) * HID + c0 + 4);
            #pragma unroll
            for (int r = 0; r < 4; r++) fma8(up[r], aq[r].x, w0, w1);
        }
        {
            float4 w0 = *(const float4*)(W_upd + (size_t)(k + 1) * HID + c0);
            float4 w1 = *(const float4*)(W_upd + (size_t)(k + 1) * HID + c0 + 4);
            #pragma unroll
            for (int r = 0; r < 4; r++) fma8(up[r], aq[r].y, w0, w1);
        }
        {
            float4 w0 = *(const float4*)(W_upd + (size_t)(k + 2) * HID + c0);
            float4 w1 = *(const float4*)(W_upd + (size_t)(k + 2) * HID + c0 + 4);
            #pragma unroll
            for (int r = 0; r < 4; r++) fma8(up[r], aq[r].z, w0, w1);
        }
        {
            float4 w0 = *(const float4*)(W_upd + (size_t)(k + 3) * HID + c0);
            float4 w1 = *(const float4*)(W_upd + (size_t)(k + 3) * HID + c0 + 4);
            #pragma unroll
            for (int r = 0; r < 4; r++) fma8(up[r], aq[r].w, w0, w1);
        }
    }
    __syncthreads();   // as consumed; buf becomes us

    #pragma unroll
    for (int r = 0; r < 4; r++) {
        int n = gq + 4 * r;
        float4 u0, u1;
        float v;
        v = up[r][0]; u0.x = v > 0.f ? v : SLOPE * v;
        v = up[r][1]; u0.y = v > 0.f ? v : SLOPE * v;
        v = up[r][2]; u0.z = v > 0.f ? v : SLOPE * v;
        v = up[r][3]; u0.w = v > 0.f ? v : SLOPE * v;
        v = up[r][4]; u1.x = v > 0.f ? v : SLOPE * v;
        v = up[r][5]; u1.y = v > 0.f ? v : SLOPE * v;
        v = up[r][6]; u1.z = v > 0.f ? v : SLOPE * v;
        v = up[r][7]; u1.w = v > 0.f ? v : SLOPE * v;
        *(float4*)&buf[n * HS_STRIDE + c0]     = u0;
        *(float4*)&buf[n * HS_STRIDE + c0 + 4] = u1;
    }
    __syncthreads();

    if (l < NB * OUT_DIM) {
        int n = l >> 1, o = l & 1;
        float s = b_cls[o];
        for (int k = 0; k < HID; k++)
            s = fmaf(buf[n * HS_STRIDE + k], W_cls[k * OUT_DIM + o], s);
        out[(size_t)(node0 + n) * OUT_DIM + o] = s;
    }
}

// ------------------------------------------------------------------ launch --
extern "C" void kernel_launch(void* const* d_in, const int* in_sizes, int n_in,
                              void* d_out, int out_size, void* d_ws, size_t ws_size,
                              hipStream_t stream)
{
    const float* x       = (const float*)d_in[0];
    const int*   ei      = (const int*)  d_in[1];   // [2, E] int32
    const float* W_in    = (const float*)d_in[2];
    const float* b_in    = (const float*)d_in[3];
    const float* W_nor   = (const float*)d_in[4];
    const float* b_nor   = (const float*)d_in[5];
    const float* W_abnor = (const float*)d_in[6];
    const float* b_abnor = (const float*)d_in[7];
    const float* W_att   = (const float*)d_in[8];
    const float* b_att   = (const float*)d_in[9];
    const float* v_att   = (const float*)d_in[10];
    const float* W_upd   = (const float*)d_in[11];
    const float* b_upd   = (const float*)d_in[12];
    const float* W_cls   = (const float*)d_in[13];
    const float* b_cls   = (const float*)d_in[14];
    float* out = (float*)d_out;

    // workspace: cnt[N] | row_start[N+1] | csr_src[E] | u[N*HID] | acc[N*HID]
    // ticket[E] aliases acc (acc is only written by gather, after fill).
    int*   cnt       = (int*)d_ws;
    int*   row_start = cnt + N_NODES;
    int*   csr_src   = row_start + (N_NODES + 1);
    float* u         = (float*)(csr_src + E_EDGES);
    float* acc       = u + (size_t)N_NODES * HID;
    int*   ticket    = (int*)acc;

    zero_int_kernel<<<(N_NODES + 255) / 256, 256, 0, stream>>>(cnt, N_NODES);
    deg_ticket_kernel<<<(E_EDGES + 255) / 256, 256, 0, stream>>>(ei + E_EDGES, cnt, ticket);
    scan_kernel<<<1, 1024, 0, stream>>>(cnt, row_start);
    fill_kernel<<<(E_EDGES + 255) / 256, 256, 0, stream>>>(ei, row_start, ticket, csr_src);
    node_phase_kernel<<<N_NODES / NB, 64, 0, stream>>>(
        x, W_in, b_in, W_nor, b_nor, W_abnor, b_abnor,
        W_att, b_att, v_att, cnt, u);
    gather_kernel<<<(N_NODES + 3) / 4, 256, 0, stream>>>(row_start, csr_src, u, acc);
    final_phase_kernel<<<N_NODES / NB, 64, 0, stream>>>(
        acc, cnt, W_upd, b_upd, W_cls, b_cls, out);
}